// Round 15
// baseline (485.444 us; speedup 1.0000x reference)
//
#include <hip/hip_runtime.h>

#define NFEAT 128
#define NGRAPHS 128
#define FCH 64
#define NCLS 10
#define ELLW 48
#define BROWS 64          // nodes per layer block
#define XPAD 132          // Xs row stride (floats): +4 pad for bank spread

// ---------------- ELL fill: cursor[d]++ allocates slot --------------
__global__ void ell_fill_kernel(const int* __restrict__ src, const int* __restrict__ dst, int E,
                                int* __restrict__ cursor, int* __restrict__ ell) {
    int i = (blockIdx.x * blockDim.x + threadIdx.x) * 4;
    if (i + 3 < E) {
        int4 s4 = *(const int4*)(src + i);
        int4 d4 = *(const int4*)(dst + i);
        int p;
        p = atomicAdd(&cursor[d4.x], 1); if (p < ELLW) ell[(size_t)d4.x * ELLW + p] = s4.x;
        p = atomicAdd(&cursor[d4.y], 1); if (p < ELLW) ell[(size_t)d4.y * ELLW + p] = s4.y;
        p = atomicAdd(&cursor[d4.z], 1); if (p < ELLW) ell[(size_t)d4.z * ELLW + p] = s4.z;
        p = atomicAdd(&cursor[d4.w], 1); if (p < ELLW) ell[(size_t)d4.w * ELLW + p] = s4.w;
    } else {
        for (int j = i; j < E; ++j) {
            int d = dst[j];
            int p = atomicAdd(&cursor[d], 1);
            if (p < ELLW) ell[(size_t)d * ELLW + p] = src[j];
        }
    }
}

// ---------------- dinv = rsqrt(deg + 1) (self loop included) --------
__global__ void dinv_kernel(const int* __restrict__ deg, float* __restrict__ dinv, int N) {
    int i = blockIdx.x * blockDim.x + threadIdx.x;
    if (i < N) dinv[i] = rsqrtf((float)(deg[i] + 1));
}

// ======== fused layer: aggregate(input) -> LDS -> GEMM -> out ========
// out = relu( (A_norm . In) . W + b ),  A_norm incl. self loops.
// Block owns nodes bid*64..+63. Phase 1 gathers agg rows into LDS
// (reads ONLY the layer input, finalized by the previous launch — no
// intra-kernel producer/consumer, no cross-XCD coherence hazard).
// Phase 2: GEMM from LDS (W staged in 16 KB chunks), bias+relu, store.
__global__ __launch_bounds__(256)
void layer_kernel(const float* __restrict__ In, const float* __restrict__ W,
                  const float* __restrict__ dinvv, const int* __restrict__ deg,
                  const int* __restrict__ ell, const float* __restrict__ bias,
                  float* __restrict__ Out, int N) {
    __shared__ float Xs[BROWS * XPAD];   // 33.8 KB aggregated rows
    __shared__ float4 Ws4[32 * 32];      // 16 KB W chunk (32 k-rows)
    int t = threadIdx.x;
    int n0 = blockIdx.x * BROWS;

    // ---------------- Phase 1: gather-aggregate into LDS ----------------
    {
        int wave = t >> 6;
        int lane = t & 63;
        int half = lane >> 5;    // 0: even edges, 1: odd edges
        int fl = lane & 31;      // float4 slot in the 128-float row
        const float4* H4 = (const float4*)In;   // row stride = 32 float4

        #pragma unroll 1
        for (int i = 0; i < BROWS / 4 / 4; ++i) {   // 4 waves x 4 iter... see below
        }
        // wave w handles nodes n0 + w*16 .. +15
        #pragma unroll 1
        for (int i = 0; i < 16; ++i) {
            int node = n0 + wave * 16 + i;
            if (node >= N) break;

            float di = dinvv[node];
            float4 acc = {0.f, 0.f, 0.f, 0.f};
            if (half == 0) {     // self term dinv_i * In[i]
                float4 h = H4[(size_t)node * 32 + fl];
                acc.x = di * h.x; acc.y = di * h.y; acc.z = di * h.z; acc.w = di * h.w;
            }

            const int* row = ell + (size_t)node * ELLW;
            int d = deg[node]; if (d > ELLW) d = ELLW;
            int e = 0;

            for (; e + 7 < d; e += 8) {
                int s0 = row[e + half], s1 = row[e + 2 + half];
                int s2 = row[e + 4 + half], s3 = row[e + 6 + half];
                float d0 = dinvv[s0], d1 = dinvv[s1], d2 = dinvv[s2], d3 = dinvv[s3];
                float4 v0 = H4[(size_t)s0 * 32 + fl];
                float4 v1 = H4[(size_t)s1 * 32 + fl];
                float4 v2 = H4[(size_t)s2 * 32 + fl];
                float4 v3 = H4[(size_t)s3 * 32 + fl];
                acc.x = fmaf(d0, v0.x, acc.x); acc.y = fmaf(d0, v0.y, acc.y);
                acc.z = fmaf(d0, v0.z, acc.z); acc.w = fmaf(d0, v0.w, acc.w);
                acc.x = fmaf(d1, v1.x, acc.x); acc.y = fmaf(d1, v1.y, acc.y);
                acc.z = fmaf(d1, v1.z, acc.z); acc.w = fmaf(d1, v1.w, acc.w);
                acc.x = fmaf(d2, v2.x, acc.x); acc.y = fmaf(d2, v2.y, acc.y);
                acc.z = fmaf(d2, v2.z, acc.z); acc.w = fmaf(d2, v2.w, acc.w);
                acc.x = fmaf(d3, v3.x, acc.x); acc.y = fmaf(d3, v3.y, acc.y);
                acc.z = fmaf(d3, v3.z, acc.z); acc.w = fmaf(d3, v3.w, acc.w);
            }
            for (; e + 1 < d; e += 2) {
                int s = row[e + half];
                float ds = dinvv[s];
                float4 v = H4[(size_t)s * 32 + fl];
                acc.x = fmaf(ds, v.x, acc.x); acc.y = fmaf(ds, v.y, acc.y);
                acc.z = fmaf(ds, v.z, acc.z); acc.w = fmaf(ds, v.w, acc.w);
            }
            if (e < d && half == 0) {
                int s = row[e];
                float ds = dinvv[s];
                float4 v = H4[(size_t)s * 32 + fl];
                acc.x = fmaf(ds, v.x, acc.x); acc.y = fmaf(ds, v.y, acc.y);
                acc.z = fmaf(ds, v.z, acc.z); acc.w = fmaf(ds, v.w, acc.w);
            }

            acc.x += __shfl_down(acc.x, 32, 64);
            acc.y += __shfl_down(acc.y, 32, 64);
            acc.z += __shfl_down(acc.z, 32, 64);
            acc.w += __shfl_down(acc.w, 32, 64);

            if (half == 0) {     // agg row = di * acc  -> LDS
                float4 o = {di * acc.x, di * acc.y, di * acc.z, di * acc.w};
                *(float4*)(&Xs[(wave * 16 + i) * XPAD + fl * 4]) = o;
            }
        }
    }
    __syncthreads();

    // ---------------- Phase 2: GEMM from LDS + bias + relu ----------------
    {
        int tx = t & 15;   // col group: cols {tx*4..+3, 64+tx*4..+3}
        int ty = t >> 4;   // row group: 4 rows
        int rl0 = ty * 4;  // local row base
        int r0 = n0 + rl0;

        float acc[4][8];
        #pragma unroll
        for (int i = 0; i < 4; ++i)
            #pragma unroll
            for (int j = 0; j < 8; ++j) acc[i][j] = 0.f;

        const float4* W4g = (const float4*)W;

        #pragma unroll 1
        for (int c = 0; c < 4; ++c) {   // 4 chunks of 32 k-rows
            #pragma unroll
            for (int j = 0; j < 4; ++j) Ws4[t + j * 256] = W4g[c * 1024 + t + j * 256];
            __syncthreads();

            #pragma unroll 2
            for (int k = 0; k < 32; k += 4) {
                float xk[4][4];
                #pragma unroll
                for (int i = 0; i < 4; ++i) {
                    float4 v = *(const float4*)(&Xs[(rl0 + i) * XPAD + c * 32 + k]);
                    xk[i][0] = v.x; xk[i][1] = v.y; xk[i][2] = v.z; xk[i][3] = v.w;
                }
                #pragma unroll
                for (int kk = 0; kk < 4; ++kk) {
                    float4 wa = Ws4[(k + kk) * 32 + tx];
                    float4 wb = Ws4[(k + kk) * 32 + 16 + tx];
                    float w[8] = {wa.x, wa.y, wa.z, wa.w, wb.x, wb.y, wb.z, wb.w};
                    #pragma unroll
                    for (int i = 0; i < 4; ++i) {
                        float xv = xk[i][kk];
                        #pragma unroll
                        for (int j = 0; j < 8; ++j) acc[i][j] = fmaf(xv, w[j], acc[i][j]);
                    }
                }
            }
            __syncthreads();
        }

        float4 ba = ((const float4*)bias)[tx];
        float4 bb = ((const float4*)bias)[16 + tx];
        #pragma unroll
        for (int i = 0; i < 4; ++i) {
            if (r0 + i < N) {
                float* hp = Out + (size_t)(r0 + i) * NFEAT;
                float4 o0 = {fmaxf(acc[i][0] + ba.x, 0.f), fmaxf(acc[i][1] + ba.y, 0.f),
                             fmaxf(acc[i][2] + ba.z, 0.f), fmaxf(acc[i][3] + ba.w, 0.f)};
                float4 o1 = {fmaxf(acc[i][4] + bb.x, 0.f), fmaxf(acc[i][5] + bb.y, 0.f),
                             fmaxf(acc[i][6] + bb.z, 0.f), fmaxf(acc[i][7] + bb.w, 0.f)};
                *(float4*)(hp + tx * 4) = o0;
                *(float4*)(hp + 64 + tx * 4) = o1;
            }
        }
    }
}

// ------- fused pool (batch sorted, binary search) + FC head ---------
__global__ __launch_bounds__(256)
void poolfc_kernel(const float* __restrict__ H, const int* __restrict__ batch, int N,
                   const float* __restrict__ Wf1, const float* __restrict__ bf1,
                   const float* __restrict__ Wf2, const float* __restrict__ bf2,
                   float* __restrict__ out) {
    int g = blockIdx.x;

    int lo = 0, hi = N;
    while (lo < hi) { int mid = (lo + hi) >> 1; if (batch[mid] < g) lo = mid + 1; else hi = mid; }
    int start = lo;
    hi = N;
    while (lo < hi) { int mid = (lo + hi) >> 1; if (batch[mid] < g + 1) lo = mid + 1; else hi = mid; }
    int end = lo;

    int wave = threadIdx.x >> 6;
    int lane = threadIdx.x & 63;

    float2 acc = {0.f, 0.f};
    for (int i = start + wave; i < end; i += 4) {
        float2 v = ((const float2*)(H + (size_t)i * NFEAT))[lane];
        acc.x += v.x; acc.y += v.y;
    }

    __shared__ float2 part[4][64];
    __shared__ float hg[NFEAT];
    __shared__ float h1[FCH];
    part[wave][lane] = acc;
    __syncthreads();

    if (wave == 0) {
        float2 t0 = part[0][lane], t1 = part[1][lane], t2 = part[2][lane], t3 = part[3][lane];
        float c = fmaxf((float)(end - start), 1.0f);
        hg[lane * 2]     = (t0.x + t1.x + t2.x + t3.x) / c;
        hg[lane * 2 + 1] = (t0.y + t1.y + t2.y + t3.y) / c;
        float a = bf1[lane];
        #pragma unroll 4
        for (int k = 0; k < NFEAT; ++k) a = fmaf(hg[k], Wf1[k * FCH + lane], a);
        h1[lane] = fmaxf(a, 0.f);
        if (lane < NCLS) {
            float o = bf2[lane];
            #pragma unroll
            for (int j = 0; j < FCH; ++j) o = fmaf(h1[j], Wf2[j * NCLS + lane], o);
            out[g * NCLS + lane] = o;
        }
    }
}

extern "C" void kernel_launch(void* const* d_in, const int* in_sizes, int n_in,
                              void* d_out, int out_size, void* d_ws, size_t ws_size,
                              hipStream_t stream) {
    const float* x   = (const float*)d_in[0];
    const int*   ei  = (const int*)d_in[1];
    const int*   bat = (const int*)d_in[2];
    const float* W1  = (const float*)d_in[3];
    const float* b1  = (const float*)d_in[4];
    const float* W2  = (const float*)d_in[5];
    const float* b2  = (const float*)d_in[6];
    const float* W3  = (const float*)d_in[7];
    const float* b3  = (const float*)d_in[8];
    const float* Wf1 = (const float*)d_in[9];
    const float* bf1 = (const float*)d_in[10];
    const float* Wf2 = (const float*)d_in[11];
    const float* bf2 = (const float*)d_in[12];
    float* out = (float*)d_out;

    int N = in_sizes[0] / NFEAT;
    int E = in_sizes[1] / 2;
    const int* src = ei;
    const int* dst = ei + E;

    char* ws = (char*)d_ws;
    size_t off = 0;
    auto align256 = [](size_t v) { return (v + 255) & ~(size_t)255; };

    int* cursor = (int*)(ws + off);              // N ints (doubles as deg)
    off = align256(off + (size_t)N * 4);
    int* ell = (int*)(ws + off);                 // N*ELLW ints
    off = align256(off + (size_t)N * ELLW * 4);
    float* dinv = (float*)(ws + off);            // N floats
    off = align256(off + (size_t)N * 4);
    float* h0 = (float*)(ws + off);              // N*128 floats
    off = align256(off + (size_t)N * NFEAT * 4);
    float* h1 = (float*)(ws + off);              // N*128 floats
    off = align256(off + (size_t)N * NFEAT * 4);

    hipMemsetAsync(cursor, 0, (size_t)N * 4, stream);

    int tpb = 256;
    int e4blocks = ((E + 3) / 4 + tpb - 1) / tpb;
    int nblocks = (N + tpb - 1) / tpb;

    ell_fill_kernel<<<e4blocks, tpb, 0, stream>>>(src, dst, E, cursor, ell);
    dinv_kernel<<<nblocks, tpb, 0, stream>>>(cursor, dinv, N);

    int layer_blocks = (N + BROWS - 1) / BROWS;

    // layer 1: x -> h0;  layer 2: h0 -> h1;  layer 3: h1 -> h0
    layer_kernel<<<layer_blocks, 256, 0, stream>>>(x,  W1, dinv, cursor, ell, b1, h0, N);
    layer_kernel<<<layer_blocks, 256, 0, stream>>>(h0, W2, dinv, cursor, ell, b2, h1, N);
    layer_kernel<<<layer_blocks, 256, 0, stream>>>(h1, W3, dinv, cursor, ell, b3, h0, N);

    // fused pooling + head
    poolfc_kernel<<<NGRAPHS, 256, 0, stream>>>(h0, bat, N, Wf1, bf1, Wf2, bf2, out);
}

// Round 16
// 440.979 us; speedup vs baseline: 1.1008x; 1.1008x over previous
//
#include <hip/hip_runtime.h>

#define NFEAT 128
#define NGRAPHS 128
#define FCH 64
#define NCLS 10
#define ELLW 48

// ---------------- ELL fill: cursor[d]++ allocates slot --------------
__global__ void ell_fill_kernel(const int* __restrict__ src, const int* __restrict__ dst, int E,
                                int* __restrict__ cursor, int* __restrict__ ell) {
    int i = (blockIdx.x * blockDim.x + threadIdx.x) * 4;
    if (i + 3 < E) {
        int4 s4 = *(const int4*)(src + i);
        int4 d4 = *(const int4*)(dst + i);
        int p;
        p = atomicAdd(&cursor[d4.x], 1); if (p < ELLW) ell[(size_t)d4.x * ELLW + p] = s4.x;
        p = atomicAdd(&cursor[d4.y], 1); if (p < ELLW) ell[(size_t)d4.y * ELLW + p] = s4.y;
        p = atomicAdd(&cursor[d4.z], 1); if (p < ELLW) ell[(size_t)d4.z * ELLW + p] = s4.z;
        p = atomicAdd(&cursor[d4.w], 1); if (p < ELLW) ell[(size_t)d4.w * ELLW + p] = s4.w;
    } else {
        for (int j = i; j < E; ++j) {
            int d = dst[j];
            int p = atomicAdd(&cursor[d], 1);
            if (p < ELLW) ell[(size_t)d * ELLW + p] = src[j];
        }
    }
}

// ---- GEMM, no LDS: h'[r,:] = rsqrt(deg[r]+1) * (X[r,:] @ W) --------
// 64 rows/block, 256 threads: tx = t&31 (cols tx*4..+3), ty = t>>5
// (rows ty*8..+7). W read directly from L1/L2 (64 KB, L2-resident;
// per-wave W4 row read = 512B contiguous). No barriers, free-running.
__global__ __launch_bounds__(256)
void gemm128_kernel(const float* __restrict__ X, const float* __restrict__ W,
                    const int* __restrict__ deg, float* __restrict__ H, int N) {
    int t = threadIdx.x;
    int tx = t & 31;   // col group: cols tx*4..+3
    int ty = t >> 5;   // row group: 8 rows
    int r0 = blockIdx.x * 64 + ty * 8;

    const float4* W4 = (const float4*)W;

    const float* xr[8];
    bool rowok[8];
    #pragma unroll
    for (int i = 0; i < 8; ++i) {
        rowok[i] = (r0 + i < N);
        xr[i] = X + (size_t)(rowok[i] ? (r0 + i) : 0) * NFEAT;
    }

    float acc[8][4];
    #pragma unroll
    for (int i = 0; i < 8; ++i)
        #pragma unroll
        for (int j = 0; j < 4; ++j) acc[i][j] = 0.f;

    #pragma unroll 2
    for (int k0 = 0; k0 < 128; k0 += 4) {
        float4 xv[8];
        #pragma unroll
        for (int i = 0; i < 8; ++i) xv[i] = *(const float4*)(xr[i] + k0);  // broadcast across 32 lanes
        #pragma unroll
        for (int kk = 0; kk < 4; ++kk) {
            float4 w4 = W4[(k0 + kk) * 32 + tx];   // L1-hit after first wave
            #pragma unroll
            for (int i = 0; i < 8; ++i) {
                float xs = (kk == 0) ? xv[i].x : (kk == 1) ? xv[i].y : (kk == 2) ? xv[i].z : xv[i].w;
                acc[i][0] = fmaf(xs, w4.x, acc[i][0]);
                acc[i][1] = fmaf(xs, w4.y, acc[i][1]);
                acc[i][2] = fmaf(xs, w4.z, acc[i][2]);
                acc[i][3] = fmaf(xs, w4.w, acc[i][3]);
            }
        }
    }

    #pragma unroll
    for (int i = 0; i < 8; ++i) {
        if (rowok[i]) {
            float di = rsqrtf((float)(deg[r0 + i] + 1));
            float4 o = {di * acc[i][0], di * acc[i][1], di * acc[i][2], di * acc[i][3]};
            *(float4*)(H + (size_t)(r0 + i) * NFEAT + tx * 4) = o;
        }
    }
}

// ---------------- pull aggregation over ELL, prescaled H ------------
// out[i] = relu( dinv[i]*( h'[i] + sum_{s} h'[s] ) + b ),  h' = dinv*h
// float4/lane, 2 edges per wave-step (lanes 0-31 even edge, 32-63 odd).
__global__ __launch_bounds__(256)
void aggregate_kernel(const float* __restrict__ Hs, const int* __restrict__ deg,
                      const int* __restrict__ ell,
                      const float* __restrict__ bias, float* __restrict__ out, int N) {
    int node = (blockIdx.x * 256 + threadIdx.x) >> 6;
    int lane = threadIdx.x & 63;
    if (node >= N) return;

    int half = lane >> 5;
    int fl = lane & 31;
    const float4* H4 = (const float4*)Hs;   // row stride = 32 float4

    int dn = deg[node];
    float di = rsqrtf((float)(dn + 1));
    float4 acc = {0.f, 0.f, 0.f, 0.f};
    if (half == 0) acc = H4[(size_t)node * 32 + fl];   // self term h'_i

    const int* row = ell + (size_t)node * ELLW;
    int d = dn; if (d > ELLW) d = ELLW;
    int e = 0;

    for (; e + 7 < d; e += 8) {
        int s0 = row[e + half], s1 = row[e + 2 + half];
        int s2 = row[e + 4 + half], s3 = row[e + 6 + half];
        float4 v0 = H4[(size_t)s0 * 32 + fl];
        float4 v1 = H4[(size_t)s1 * 32 + fl];
        float4 v2 = H4[(size_t)s2 * 32 + fl];
        float4 v3 = H4[(size_t)s3 * 32 + fl];
        acc.x += v0.x + v1.x + v2.x + v3.x;
        acc.y += v0.y + v1.y + v2.y + v3.y;
        acc.z += v0.z + v1.z + v2.z + v3.z;
        acc.w += v0.w + v1.w + v2.w + v3.w;
    }
    for (; e + 1 < d; e += 2) {
        int s = row[e + half];
        float4 v = H4[(size_t)s * 32 + fl];
        acc.x += v.x; acc.y += v.y; acc.z += v.z; acc.w += v.w;
    }
    if (e < d && half == 0) {
        int s = row[e];
        float4 v = H4[(size_t)s * 32 + fl];
        acc.x += v.x; acc.y += v.y; acc.z += v.z; acc.w += v.w;
    }

    acc.x += __shfl_down(acc.x, 32, 64);
    acc.y += __shfl_down(acc.y, 32, 64);
    acc.z += __shfl_down(acc.z, 32, 64);
    acc.w += __shfl_down(acc.w, 32, 64);

    if (half == 0) {
        float4 b = ((const float4*)bias)[fl];
        float4 o;
        o.x = fmaxf(fmaf(di, acc.x, b.x), 0.f);
        o.y = fmaxf(fmaf(di, acc.y, b.y), 0.f);
        o.z = fmaxf(fmaf(di, acc.z, b.z), 0.f);
        o.w = fmaxf(fmaf(di, acc.w, b.w), 0.f);
        ((float4*)(out + (size_t)node * NFEAT))[fl] = o;
    }
}

// ------- fused pool (batch sorted, binary search) + FC head ---------
// 1024 threads (16 waves) per graph for 4x pooling BW.
__global__ __launch_bounds__(1024)
void poolfc_kernel(const float* __restrict__ H, const int* __restrict__ batch, int N,
                   const float* __restrict__ Wf1, const float* __restrict__ bf1,
                   const float* __restrict__ Wf2, const float* __restrict__ bf2,
                   float* __restrict__ out) {
    int g = blockIdx.x;

    int lo = 0, hi = N;
    while (lo < hi) { int mid = (lo + hi) >> 1; if (batch[mid] < g) lo = mid + 1; else hi = mid; }
    int start = lo;
    hi = N;
    while (lo < hi) { int mid = (lo + hi) >> 1; if (batch[mid] < g + 1) lo = mid + 1; else hi = mid; }
    int end = lo;

    int wave = threadIdx.x >> 6;   // 0..15
    int lane = threadIdx.x & 63;

    float2 acc = {0.f, 0.f};
    for (int i = start + wave; i < end; i += 16) {
        float2 v = ((const float2*)(H + (size_t)i * NFEAT))[lane];
        acc.x += v.x; acc.y += v.y;
    }

    __shared__ float2 part[16][64];
    __shared__ float hg[NFEAT];
    __shared__ float h1[FCH];
    part[wave][lane] = acc;
    __syncthreads();

    if (wave == 0) {
        float2 tot = {0.f, 0.f};
        #pragma unroll
        for (int w = 0; w < 16; ++w) { tot.x += part[w][lane].x; tot.y += part[w][lane].y; }
        float c = fmaxf((float)(end - start), 1.0f);
        hg[lane * 2]     = tot.x / c;
        hg[lane * 2 + 1] = tot.y / c;
        float a = bf1[lane];
        #pragma unroll 4
        for (int k = 0; k < NFEAT; ++k) a = fmaf(hg[k], Wf1[k * FCH + lane], a);
        h1[lane] = fmaxf(a, 0.f);
        if (lane < NCLS) {
            float o = bf2[lane];
            #pragma unroll
            for (int j = 0; j < FCH; ++j) o = fmaf(h1[j], Wf2[j * NCLS + lane], o);
            out[g * NCLS + lane] = o;
        }
    }
}

extern "C" void kernel_launch(void* const* d_in, const int* in_sizes, int n_in,
                              void* d_out, int out_size, void* d_ws, size_t ws_size,
                              hipStream_t stream) {
    const float* x   = (const float*)d_in[0];
    const int*   ei  = (const int*)d_in[1];
    const int*   bat = (const int*)d_in[2];
    const float* W1  = (const float*)d_in[3];
    const float* b1  = (const float*)d_in[4];
    const float* W2  = (const float*)d_in[5];
    const float* b2  = (const float*)d_in[6];
    const float* W3  = (const float*)d_in[7];
    const float* b3  = (const float*)d_in[8];
    const float* Wf1 = (const float*)d_in[9];
    const float* bf1 = (const float*)d_in[10];
    const float* Wf2 = (const float*)d_in[11];
    const float* bf2 = (const float*)d_in[12];
    float* out = (float*)d_out;

    int N = in_sizes[0] / NFEAT;
    int E = in_sizes[1] / 2;
    const int* src = ei;
    const int* dst = ei + E;

    char* ws = (char*)d_ws;
    size_t off = 0;
    auto align256 = [](size_t v) { return (v + 255) & ~(size_t)255; };

    int* cursor = (int*)(ws + off);              // N ints (degree histogram)
    off = align256(off + (size_t)N * 4);
    int* ell = (int*)(ws + off);                 // N*ELLW ints
    off = align256(off + (size_t)N * ELLW * 4);
    float* h0 = (float*)(ws + off);              // N*128 floats (prescaled h')
    off = align256(off + (size_t)N * NFEAT * 4);
    float* h1 = (float*)(ws + off);              // N*128 floats (layer out)
    off = align256(off + (size_t)N * NFEAT * 4);

    hipMemsetAsync(cursor, 0, (size_t)N * 4, stream);

    int tpb = 256;
    int e4blocks = ((E + 3) / 4 + tpb - 1) / tpb;

    ell_fill_kernel<<<e4blocks, tpb, 0, stream>>>(src, dst, E, cursor, ell);

    int gemm_blocks = (N + 63) / 64;
    int agg_blocks = (N + 3) / 4;  // 4 wave64 per 256-thread block

    // layer 1
    gemm128_kernel<<<gemm_blocks, 256, 0, stream>>>(x, W1, cursor, h0, N);
    aggregate_kernel<<<agg_blocks, 256, 0, stream>>>(h0, cursor, ell, b1, h1, N);
    // layer 2
    gemm128_kernel<<<gemm_blocks, 256, 0, stream>>>(h1, W2, cursor, h0, N);
    aggregate_kernel<<<agg_blocks, 256, 0, stream>>>(h0, cursor, ell, b2, h1, N);
    // layer 3
    gemm128_kernel<<<gemm_blocks, 256, 0, stream>>>(h1, W3, cursor, h0, N);
    aggregate_kernel<<<agg_blocks, 256, 0, stream>>>(h0, cursor, ell, b3, h1, N);

    // fused pooling + head
    poolfc_kernel<<<NGRAPHS, 1024, 0, stream>>>(h1, bat, N, Wf1, bf1, Wf2, bf2, out);
}